// Round 1
// baseline (557.193 us; speedup 1.0000x reference)
//
#include <hip/hip_runtime.h>

// B=32 H=8 NQ=64 NK=4096 DIN=512 DV=64 DM=512
typedef short bf16x8 __attribute__((ext_vector_type(8)));
typedef short bf16x4 __attribute__((ext_vector_type(4)));
typedef float f32x4 __attribute__((ext_vector_type(4)));
typedef unsigned int u32x2 __attribute__((ext_vector_type(2)));
typedef unsigned int u32x4 __attribute__((ext_vector_type(4)));

__device__ __forceinline__ unsigned short f2bf(float f) {
  union { float f; unsigned u; } v; v.f = f;
  unsigned r = v.u + 0x7fffu + ((v.u >> 16) & 1u);   // RNE
  return (unsigned short)(r >> 16);
}

// pack two fp32 -> bf16x2 (round-to-nearest, ties up): 2 v_add + 1 v_perm
__device__ __forceinline__ unsigned int pk2(float a, float b) {
  union { float f; unsigned u; } x, y; x.f = a; y.f = b;
  return __builtin_amdgcn_perm(y.u + 0x8000u, x.u + 0x8000u, 0x07060302u);
}

__device__ __forceinline__ void gld_lds16(const void* g, void* l) {
  __builtin_amdgcn_global_load_lds(
      (const __attribute__((address_space(1))) void*)g,
      (__attribute__((address_space(3))) void*)l, 16, 0, 0);
}

// ---------------------------------------------------------------------------
// prep: Wv->bf16 (blocks 0-255), Wo->bf16 (256-511), bias2 (512-513)
// bias2[e] = b_o[e] + sum_d b_v[d]*W_o[e][d]  (exact: softmax rows sum to 1)
__global__ __launch_bounds__(256) void prep(const float* __restrict__ W_v,
                                            const float* __restrict__ W_o,
                                            const float* __restrict__ b_v,
                                            const float* __restrict__ b_o,
                                            unsigned short* __restrict__ Wvb,
                                            unsigned short* __restrict__ Wob,
                                            float* __restrict__ bias2) {
  int bid = blockIdx.x;
  if (bid < 512) {
    const float* in = (bid < 256) ? W_v : W_o;
    unsigned short* out = (bid < 256) ? Wvb : Wob;
    long i = (long)((bid & 255) * 256 + threadIdx.x) * 4;
    f32x4 d = *(const f32x4*)(in + i);
    u32x2 w; w[0] = pk2(d[0], d[1]); w[1] = pk2(d[2], d[3]);
    *(u32x2*)(out + i) = w;
  } else {
    int e = (bid - 512) * 256 + threadIdx.x;
    const float* wrow = W_o + (long)e * 512;
    float s = 0.f;
#pragma unroll 4
    for (int d = 0; d < 512; d += 4) {
      f32x4 w = *(const f32x4*)(wrow + d);
      f32x4 bv = *(const f32x4*)(b_v + d);
      s += w[0] * bv[0] + w[1] * bv[1] + w[2] * bv[2] + w[3] * bv[3];
    }
    bias2[e] = s + b_o[e];
  }
}

// ---------------------------------------------------------------------------
// vT[b][d][nk] = sum_c Wv[d][c] * V[b][nk][c]  (bf16 out)
// T4 counted-vmcnt pipeline: raw s_barrier (NO vmcnt(0) drain), As
// triple-buffered (asyncA 2 iters deep), breg double-banked (loadB 2 deep).
// Steady-state FIFO at the pre-barrier wait:
//   {asyncA(r):2, loadB(r+1):4, asyncA(r+1):2, loadB(r+2):4} = 12 outstanding
//   -> s_waitcnt vmcnt(10) retires exactly asyncA(r) (FIFO in-order retire).
// Memory-clobber asm fences pin issue order so the count is exact.
__global__ __launch_bounds__(256, 2) void vt_gemm(
    const unsigned short* __restrict__ Wvb, const float* __restrict__ V,
    unsigned short* __restrict__ vT) {
  const int t = threadIdx.x, lane = t & 63, wave = t >> 6;
  const int n0 = blockIdx.x * 128;   // nk
  const int m0 = blockIdx.y * 128;   // d
  const int b = blockIdx.z;
  const float* Vb = V + (long)b * (4096L * 512) + (long)n0 * 512;

  __shared__ __align__(16) unsigned short As[3][128 * 32];  // 24 KB, triple
  __shared__ __align__(16) unsigned short Bs[2][128 * 32];  // 16 KB, double

  const int wm = (wave >> 1) * 64, wn = (wave & 1) * 64;
  const int l16 = lane & 15, quad = lane >> 4;
  const int brow0 = t >> 3, bc4 = (t & 7) * 4;   // B: 8 lanes/row, coalesced

  f32x4 breg[2][4];
  auto loadB = [&](int rr, int bank) {
    const int k0 = (rr < 16) ? rr * 32 : 0;   // clamp: uniform dummy at tail
#pragma unroll
    for (int j = 0; j < 4; ++j)
      breg[bank][j] = *(const f32x4*)(Vb + (long)(brow0 + 32 * j) * 512 + k0 + bc4);
  };
  auto asyncA = [&](int rr, int slot) {
    const int k0 = (rr < 16) ? rr * 32 : 0;
#pragma unroll
    for (int s = 0; s < 2; ++s) {
      int li = s * 256 + t;
      int row = li >> 2, kq = (li & 3) * 8;
      gld_lds16(Wvb + (long)(m0 + row) * 512 + k0 + kq,
                (char*)&As[slot][0] + (s * 256 + wave * 64) * 16);
    }
  };

  f32x4 acc[4][4];
#pragma unroll
  for (int i = 0; i < 4; ++i)
#pragma unroll
    for (int j = 0; j < 4; ++j) acc[i][j] = (f32x4){0.f, 0.f, 0.f, 0.f};

  asyncA(0, 0);
  loadB(0, 0);
  asyncA(1, 1);
  loadB(1, 1);

  int slotR = 0, slotW = 2;
  for (int r = 0; r < 16; ++r) {
    const int bank = r & 1;
    // pack breg(r) -> Bs[bank]; compiler auto-waits only loadB(r)'s 4 loads
    // (they are OLDER than asyncA(r) in FIFO, so the deep pipe is preserved)
#pragma unroll
    for (int j = 0; j < 4; ++j) {
      u32x2 w;
      w[0] = pk2(breg[bank][j][0], breg[bank][j][1]);
      w[1] = pk2(breg[bank][j][2], breg[bank][j][3]);
      *(u32x2*)(&Bs[bank][(brow0 + 32 * j) * 32 + bc4]) = w;
    }
    loadB(r + 2, bank);   // refill freed bank, consumed at iter r+2
    // own ds_writes done + asyncA(r) landed; keep 10 younger ops in flight
    asm volatile("s_waitcnt vmcnt(10) lgkmcnt(0)" ::: "memory");
    __builtin_amdgcn_s_barrier();
    asm volatile("" ::: "memory");
    asyncA(r + 2, slotW);   // slot last read at iter r-1: safe after barrier(r)
    asm volatile("" ::: "memory");
    bf16x8 af[4], bfv[4];
#pragma unroll
    for (int i = 0; i < 4; ++i)
      af[i] = *(const bf16x8*)(&As[slotR][(wm + i * 16 + l16) * 32 + quad * 8]);
#pragma unroll
    for (int j = 0; j < 4; ++j)
      bfv[j] = *(const bf16x8*)(&Bs[bank][(wn + j * 16 + l16) * 32 + quad * 8]);
#pragma unroll
    for (int i = 0; i < 4; ++i)
#pragma unroll
      for (int j = 0; j < 4; ++j)
        acc[i][j] = __builtin_amdgcn_mfma_f32_16x16x32_bf16(af[i], bfv[j], acc[i][j], 0, 0, 0);
    slotR = (slotR == 2) ? 0 : slotR + 1;
    slotW = (slotW == 2) ? 0 : slotW + 1;
  }
  asm volatile("s_waitcnt vmcnt(0)" ::: "memory");   // drain tail dummies

  unsigned short* o = vT + (long)b * 2097152;
#pragma unroll
  for (int i = 0; i < 4; ++i)
#pragma unroll
    for (int j = 0; j < 4; ++j) {
      int col = n0 + wn + j * 16 + l16;
#pragma unroll
      for (int r = 0; r < 4; ++r) {
        int row = m0 + wm + i * 16 + quad * 4 + r;
        o[(long)row * 4096 + col] = f2bf(acc[i][j][r]);
      }
    }
}

// ---------------------------------------------------------------------------
// Fused attention per (b,h): U[b][q][h*64+dv] = (1/Z_q) sum_k exp(a12*a3)*vT[d][k]
// T4 counted-vmcnt pipeline (1 block/CU: drains were fully exposed here).
// Bs triple-buffered (asyncB 2 deep); steady FIFO at pre-barrier wait:
//   {asyncB(r):4, asyncB(r+1):4} = 8 -> vmcnt(4) retires exactly asyncB(r).
// As rows padded 32->40 shorts (80 B): staging ds_write was a 32-way bank
// conflict (64 lanes x 64-B stride); pad cuts write to 8-way.
__global__ __launch_bounds__(256, 2) void o_gemm(
    const float* __restrict__ att12, const float* __restrict__ att3,
    const unsigned short* __restrict__ vT, unsigned short* __restrict__ U) {
  const int bh = blockIdx.x;
  const int b = bh >> 3, h = bh & 7;
  const int t = threadIdx.x, lane = t & 63, wave = t >> 6;

  __shared__ __align__(16) unsigned short As[2][4 * 64 * 40];  // 40 KB padded
  __shared__ __align__(16) unsigned short Bs[3][4 * 64 * 32];  // 48 KB triple
  __shared__ float Ored[64 * 68];
  __shared__ float Zl[4][64];
  __shared__ float rZa[64];

  const unsigned short* vTb = vT + (long)b * 2097152 + (long)h * 64 * 4096;
  const int gq = t & 63, gw = t >> 6;          // A-gen: (k-window = wave, q)
  const float* a3row = att3 + ((long)bh * 64 + gq) * 256;
  const float* a12b = att12 + (long)b * 32768 + h * 16;
  const int l16 = lane & 15, quad = lane >> 4;

  f32x4 acc[4][4];
#pragma unroll
  for (int i = 0; i < 4; ++i)
#pragma unroll
    for (int j = 0; j < 4; ++j) acc[i][j] = (f32x4){0.f, 0.f, 0.f, 0.f};
  float zacc = 0.f;

  unsigned int pk[16];
  auto genexp = [&](int r) {
    int kbase = gw * 1024 + r * 32;
    int ch = kbase >> 8, fh = (kbase >> 6) & 3, cw0 = (kbase >> 2) & 15;
    f32x4 y0 = *(const f32x4*)(a3row + ch * 16 + cw0);
    f32x4 y1 = *(const f32x4*)(a3row + ch * 16 + cw0 + 4);
    const float* ap = a12b + ch * 2048 + cw0 * 128 + fh * 4;
#pragma unroll
    for (int cw = 0; cw < 8; ++cw) {
      float y = (cw < 4) ? y0[cw] : y1[cw - 4];
      f32x4 x = *(const f32x4*)(ap + cw * 128);
      float e0 = __expf(x[0] * y), e1 = __expf(x[1] * y);
      float e2 = __expf(x[2] * y), e3 = __expf(x[3] * y);
      zacc += (e0 + e1) + (e2 + e3);
      pk[cw * 2] = pk2(e0, e1);
      pk[cw * 2 + 1] = pk2(e2, e3);
    }
  };
  auto asyncB = [&](int rr, int slot) {
    const int rc = (rr < 32) ? rr : 0;   // clamp: uniform dummy at tail
#pragma unroll
    for (int s = 0; s < 4; ++s) {
      int row = t >> 2, kq = (t & 3) * 8;
      int kk = s * 1024 + rc * 32 + kq;
      gld_lds16(vTb + (long)row * 4096 + kk, (char*)&Bs[slot][0] + s * 4096 + wave * 1024);
    }
  };

  asyncB(0, 0);
  asyncB(1, 1);
  genexp(0);

  int slotR = 0, slotW = 2;
  for (int r = 0; r < 32; ++r) {
    const int abuf = r & 1;
    // write exps(r) regs -> As[abuf] (padded rows: 8-way instead of 32-way)
    {
      unsigned short* dst = &As[abuf][gw * 2560 + gq * 40];
#pragma unroll
      for (int g = 0; g < 4; ++g)
        *(u32x4*)(dst + g * 8) = (u32x4){pk[g * 4], pk[g * 4 + 1], pk[g * 4 + 2], pk[g * 4 + 3]};
    }
    // own ds_writes done + asyncB(r) landed; asyncB(r+1) stays in flight
    asm volatile("s_waitcnt vmcnt(4) lgkmcnt(0)" ::: "memory");
    __builtin_amdgcn_s_barrier();
    asm volatile("" ::: "memory");
    asyncB(r + 2, slotW);   // slot last read at iter r-1: safe after barrier(r)
    asm volatile("" ::: "memory");
    bf16x8 af[4], bfv[4];
#pragma unroll
    for (int i = 0; i < 4; ++i)
      af[i] = *(const bf16x8*)(&As[abuf][wave * 2560 + (i * 16 + l16) * 40 + quad * 8]);
#pragma unroll
    for (int j = 0; j < 4; ++j)
      bfv[j] = *(const bf16x8*)(&Bs[slotR][wave * 2048 + (j * 16 + l16) * 32 + quad * 8]);
#pragma unroll
    for (int i = 0; i < 4; ++i)
#pragma unroll
      for (int j = 0; j < 4; ++j)
        acc[i][j] = __builtin_amdgcn_mfma_f32_16x16x32_bf16(af[i], bfv[j], acc[i][j], 0, 0, 0);
    if (r < 31) genexp(r + 1);   // VALU overlaps MFMA execution
    slotR = (slotR == 2) ? 0 : slotR + 1;
    slotW = (slotW == 2) ? 0 : slotW + 1;
  }
  asm volatile("s_waitcnt vmcnt(0)" ::: "memory");   // drain tail dummies

  Zl[gw][gq] = zacc;
  __syncthreads();
  if (t < 64) rZa[t] = 1.0f / (Zl[0][t] + Zl[1][t] + Zl[2][t] + Zl[3][t]);
  // sum the 4 wave-accumulators (disjoint k-slices) into Ored
#pragma unroll
  for (int w = 0; w < 4; ++w) {
    if (wave == w) {
#pragma unroll
      for (int i = 0; i < 4; ++i)
#pragma unroll
        for (int j = 0; j < 4; ++j) {
          int col = j * 16 + l16;
#pragma unroll
          for (int rr = 0; rr < 4; ++rr) {
            int row = i * 16 + quad * 4 + rr;
            if (w == 0) Ored[row * 68 + col] = acc[i][j][rr];
            else Ored[row * 68 + col] += acc[i][j][rr];
          }
        }
    }
    __syncthreads();
  }
  // normalize + store bf16: U[(b*64+q)*512 + h*64 + dv]
  {
    int q = t >> 2, dv0 = (t & 3) * 16;
    float rz = rZa[q];
    unsigned short* up = U + ((long)(b * 64 + q)) * 512 + h * 64 + dv0;
    u32x4 o0, o1;
#pragma unroll
    for (int j = 0; j < 4; ++j)
      o0[j] = pk2(Ored[q * 68 + dv0 + 2 * j] * rz, Ored[q * 68 + dv0 + 2 * j + 1] * rz);
#pragma unroll
    for (int j = 0; j < 4; ++j)
      o1[j] = pk2(Ored[q * 68 + dv0 + 8 + 2 * j] * rz, Ored[q * 68 + dv0 + 9 + 2 * j] * rz);
    *(u32x4*)(up) = o0;
    *(u32x4*)(up + 8) = o1;
  }
}

// ---------------------------------------------------------------------------
// Final projection: out[(b,q)][e] = U (2048x512) x Wo^T + bias2
// Same T4 protocol: triple-buffered stage 2 deep, one raw barrier per K-step.
// Steady FIFO at pre-barrier wait: {S(r):2, S(r+1):2} = 4 -> vmcnt(2).
template <int BM, int BN>
__global__ __launch_bounds__(256, 2) void gemm_bt(
    const unsigned short* __restrict__ A, const unsigned short* __restrict__ Bt,
    float* __restrict__ C, const float* __restrict__ bias,
    int K, int lda, int ldb, int ldc) {
  constexpr int BK = 32;
  const int t = threadIdx.x;
  const int lane = t & 63;
  const int wave = t >> 6;
  const int m0 = blockIdx.y * BM;
  const int n0 = blockIdx.x * BN;

  A += (long)m0 * lda;
  Bt += (long)n0 * ldb;

  __shared__ __align__(16) unsigned short As[3][BM * BK];
  __shared__ __align__(16) unsigned short Bs[3][BN * BK];

  constexpr int TM = BM / 32;
  constexpr int TN = BN / 32;
  const int wm = (wave >> 1) * (BM / 2);
  const int wn = (wave & 1) * (BN / 2);
  const int l16 = lane & 15;
  const int quad = lane >> 4;

  f32x4 acc[TM][TN];
#pragma unroll
  for (int i = 0; i < TM; ++i)
#pragma unroll
    for (int j = 0; j < TN; ++j) acc[i][j] = (f32x4){0.f, 0.f, 0.f, 0.f};

  constexpr int ASHOT = (BM * 4) / 256;
  constexpr int BSHOT = (BN * 4) / 256;
  const int NIT = K / BK;

  auto stage = [&](int rr, int slot) {
    const int k0 = ((rr < NIT) ? rr : 0) * BK;   // clamp: uniform dummy tail
#pragma unroll
    for (int s = 0; s < ASHOT; ++s) {
      int li = s * 256 + t;
      int row = li >> 2, kq = (li & 3) * 8;
      gld_lds16(A + (long)row * lda + k0 + kq,
                (char*)&As[slot][0] + (s * 256 + wave * 64) * 16);
    }
#pragma unroll
    for (int s = 0; s < BSHOT; ++s) {
      int li = s * 256 + t;
      int row = li >> 2, kq = (li & 3) * 8;
      gld_lds16(Bt + (long)row * ldb + k0 + kq,
                (char*)&Bs[slot][0] + (s * 256 + wave * 64) * 16);
    }
  };

  stage(0, 0);
  stage(1, 1);

  int slotR = 0, slotW = 2;
  for (int r = 0; r < NIT; ++r) {
    asm volatile("s_waitcnt vmcnt(2)" ::: "memory");   // stage(r) landed
    __builtin_amdgcn_s_barrier();
    asm volatile("" ::: "memory");
    stage(r + 2, slotW);
    asm volatile("" ::: "memory");
    bf16x8 af[TM], bfv[TN];
#pragma unroll
    for (int i = 0; i < TM; ++i)
      af[i] = *(const bf16x8*)(&As[slotR][(wm + i * 16 + l16) * BK + quad * 8]);
#pragma unroll
    for (int j = 0; j < TN; ++j)
      bfv[j] = *(const bf16x8*)(&Bs[slotR][(wn + j * 16 + l16) * BK + quad * 8]);
#pragma unroll
    for (int i = 0; i < TM; ++i)
#pragma unroll
      for (int j = 0; j < TN; ++j)
        acc[i][j] = __builtin_amdgcn_mfma_f32_16x16x32_bf16(af[i], bfv[j], acc[i][j], 0, 0, 0);
    slotR = (slotR == 2) ? 0 : slotR + 1;
    slotW = (slotW == 2) ? 0 : slotW + 1;
  }
  asm volatile("s_waitcnt vmcnt(0)" ::: "memory");   // drain tail dummies

#pragma unroll
  for (int i = 0; i < TM; ++i) {
#pragma unroll
    for (int j = 0; j < TN; ++j) {
      int col = wn + j * 16 + l16;
#pragma unroll
      for (int r = 0; r < 4; ++r) {
        int row = wm + i * 16 + quad * 4 + r;
        C[(long)(m0 + row) * ldc + (n0 + col)] = acc[i][j][r] + bias[n0 + col];
      }
    }
  }
}

// ---------------------------------------------------------------------------
extern "C" void kernel_launch(void* const* d_in, const int* in_sizes, int n_in,
                              void* d_out, int out_size, void* d_ws, size_t ws_size,
                              hipStream_t stream) {
  const float* att12 = (const float*)d_in[0];
  const float* att3  = (const float*)d_in[1];
  const float* values = (const float*)d_in[2];
  const float* W_v = (const float*)d_in[3];
  const float* b_v = (const float*)d_in[4];
  const float* W_o = (const float*)d_in[5];
  const float* b_o = (const float*)d_in[6];
  float* out = (float*)d_out;

  char* ws = (char*)d_ws;
  unsigned short* vT    = (unsigned short*)(ws);               // 128 MB [32][512][4096]
  unsigned short* U     = (unsigned short*)(ws + 134217728L);  // 2 MB [2048][512]
  unsigned short* Wvb   = (unsigned short*)(ws + 136314880L);  // 512 KB
  unsigned short* Wob   = (unsigned short*)(ws + 136839168L);  // 512 KB
  float*          bias2 = (float*)(ws + 137363456L);           // 2 KB

  prep<<<dim3(514), dim3(256), 0, stream>>>(W_v, W_o, b_v, b_o, Wvb, Wob, bias2);

  vt_gemm<<<dim3(32, 4, 32), dim3(256), 0, stream>>>(Wvb, values, vT);

  o_gemm<<<dim3(256), dim3(256), 0, stream>>>(att12, att3, vT, U);

  gemm_bt<64, 64><<<dim3(8, 32), dim3(256), 0, stream>>>(
      U, Wob, out, bias2, 512, 512, 512, 512);

  (void)in_sizes; (void)n_in; (void)out_size; (void)ws_size;
}

// Round 2
// 531.215 us; speedup vs baseline: 1.0489x; 1.0489x over previous
//
#include <hip/hip_runtime.h>

// B=32 H=8 NQ=64 NK=4096 DIN=512 DV=64 DM=512
typedef short bf16x8 __attribute__((ext_vector_type(8)));
typedef short bf16x4 __attribute__((ext_vector_type(4)));
typedef float f32x4 __attribute__((ext_vector_type(4)));
typedef unsigned int u32x2 __attribute__((ext_vector_type(2)));
typedef unsigned int u32x4 __attribute__((ext_vector_type(4)));

__device__ __forceinline__ unsigned short f2bf(float f) {
  union { float f; unsigned u; } v; v.f = f;
  unsigned r = v.u + 0x7fffu + ((v.u >> 16) & 1u);   // RNE
  return (unsigned short)(r >> 16);
}

// pack two fp32 -> bf16x2 (round-to-nearest, ties up): 2 v_add + 1 v_perm
__device__ __forceinline__ unsigned int pk2(float a, float b) {
  union { float f; unsigned u; } x, y; x.f = a; y.f = b;
  return __builtin_amdgcn_perm(y.u + 0x8000u, x.u + 0x8000u, 0x07060302u);
}

__device__ __forceinline__ void gld_lds16(const void* g, void* l) {
  __builtin_amdgcn_global_load_lds(
      (const __attribute__((address_space(1))) void*)g,
      (__attribute__((address_space(3))) void*)l, 16, 0, 0);
}

// ---------------------------------------------------------------------------
// prep: Wv->bf16 (blocks 0-255), Wo->bf16 (256-511), bias2 (512-513)
// bias2[e] = b_o[e] + sum_d b_v[d]*W_o[e][d]  (exact: softmax rows sum to 1)
__global__ __launch_bounds__(256) void prep(const float* __restrict__ W_v,
                                            const float* __restrict__ W_o,
                                            const float* __restrict__ b_v,
                                            const float* __restrict__ b_o,
                                            unsigned short* __restrict__ Wvb,
                                            unsigned short* __restrict__ Wob,
                                            float* __restrict__ bias2) {
  int bid = blockIdx.x;
  if (bid < 512) {
    const float* in = (bid < 256) ? W_v : W_o;
    unsigned short* out = (bid < 256) ? Wvb : Wob;
    long i = (long)((bid & 255) * 256 + threadIdx.x) * 4;
    f32x4 d = *(const f32x4*)(in + i);
    u32x2 w; w[0] = pk2(d[0], d[1]); w[1] = pk2(d[2], d[3]);
    *(u32x2*)(out + i) = w;
  } else {
    int e = (bid - 512) * 256 + threadIdx.x;
    const float* wrow = W_o + (long)e * 512;
    float s = 0.f;
#pragma unroll 4
    for (int d = 0; d < 512; d += 4) {
      f32x4 w = *(const f32x4*)(wrow + d);
      f32x4 bv = *(const f32x4*)(b_v + d);
      s += w[0] * bv[0] + w[1] * bv[1] + w[2] * bv[2] + w[3] * bv[3];
    }
    bias2[e] = s + b_o[e];
  }
}

// ---------------------------------------------------------------------------
// vT[b][d][nk] = sum_c Wv[d][c] * V[b][nk][c]  (bf16 out)
// TRAFFIC-FIRST geometry: BM=256 (d) x BN=128 (nk). The V panel (fp32, the
// expensive operand: 256 KB/panel, L3-served) is now re-read only 2x across
// d-blocks instead of 4x -> logical V traffic 1.07 GB -> 536 MB. Wv (bf16,
// 512 KB total) stays L2-resident. Round-0 schedule: single __syncthreads
// per K-step, double-buffered LDS, guarded prefetch (no dummy tail loads).
// 4 waves 2x2: per-wave 128x64 output = 8x4 fragments (acc 128 VGPR).
__global__ __launch_bounds__(256, 2) void vt_gemm(
    const unsigned short* __restrict__ Wvb, const float* __restrict__ V,
    unsigned short* __restrict__ vT) {
  const int t = threadIdx.x, lane = t & 63, wave = t >> 6;
  const int n0 = blockIdx.x * 128;   // nk
  const int m0 = blockIdx.y * 256;   // d
  const int b = blockIdx.z;
  const float* Vb = V + (long)b * (4096L * 512) + (long)n0 * 512;

  __shared__ __align__(16) unsigned short As[2][256 * 32];  // 32 KB (Wv tile)
  __shared__ __align__(16) unsigned short Bs[2][128 * 32];  // 16 KB (V tile)

  const int wm = (wave >> 1) * 128, wn = (wave & 1) * 64;
  const int l16 = lane & 15, quad = lane >> 4;
  const int brow0 = t >> 3, bc4 = (t & 7) * 4;   // B: 8 lanes/row, coalesced

  f32x4 breg[4];
  auto loadB = [&](int k0) {
#pragma unroll
    for (int j = 0; j < 4; ++j)
      breg[j] = *(const f32x4*)(Vb + (long)(brow0 + 32 * j) * 512 + k0 + bc4);
  };
  auto asyncA = [&](int k0, int buf) {
#pragma unroll
    for (int s = 0; s < 4; ++s) {
      int li = s * 256 + t;
      int row = li >> 2, kq = (li & 3) * 8;
      gld_lds16(Wvb + (long)(m0 + row) * 512 + k0 + kq,
                (char*)&As[buf][0] + (s * 256 + wave * 64) * 16);
    }
  };

  f32x4 acc[8][4];
#pragma unroll
  for (int i = 0; i < 8; ++i)
#pragma unroll
    for (int j = 0; j < 4; ++j) acc[i][j] = (f32x4){0.f, 0.f, 0.f, 0.f};

  asyncA(0, 0);
  loadB(0);

  for (int r = 0; r < 16; ++r) {
    const int buf = r & 1;
    // stage B(r): pack prefetched regs -> Bs[buf] (prev readers of Bs[buf]
    // were iter r-2, separated by barrier r-1)
#pragma unroll
    for (int j = 0; j < 4; ++j) {
      u32x2 w;
      w[0] = pk2(breg[j][0], breg[j][1]);
      w[1] = pk2(breg[j][2], breg[j][3]);
      *(u32x2*)(&Bs[buf][(brow0 + 32 * j) * 32 + bc4]) = w;
    }
    __syncthreads();   // drains asyncA(r) + makes Bs[buf] visible
    if (r < 15) {      // prefetch r+1: in flight across the MFMA phase
      loadB((r + 1) * 32);
      asyncA((r + 1) * 32, buf ^ 1);
    }
    bf16x8 bfv[4];
#pragma unroll
    for (int j = 0; j < 4; ++j)
      bfv[j] = *(const bf16x8*)(&Bs[buf][(wn + j * 16 + l16) * 32 + quad * 8]);
#pragma unroll
    for (int i = 0; i < 8; ++i) {
      bf16x8 af = *(const bf16x8*)(&As[buf][(wm + i * 16 + l16) * 32 + quad * 8]);
#pragma unroll
      for (int j = 0; j < 4; ++j)
        acc[i][j] = __builtin_amdgcn_mfma_f32_16x16x32_bf16(af, bfv[j], acc[i][j], 0, 0, 0);
    }
  }

  unsigned short* o = vT + (long)b * 2097152;
#pragma unroll
  for (int i = 0; i < 8; ++i)
#pragma unroll
    for (int j = 0; j < 4; ++j) {
      int col = n0 + wn + j * 16 + l16;
#pragma unroll
      for (int r = 0; r < 4; ++r) {
        int row = m0 + wm + i * 16 + quad * 4 + r;
        o[(long)row * 4096 + col] = f2bf(acc[i][j][r]);
      }
    }
}

// ---------------------------------------------------------------------------
// Fused attention per (b,h): U[b][q][h*64+dv] = (1/Z_q) sum_k exp(a12*a3)*vT[d][k]
// T4 counted-vmcnt pipeline (1 block/CU: drains were fully exposed here).
// Bs triple-buffered (asyncB 2 deep); steady FIFO at pre-barrier wait:
//   {asyncB(r):4, asyncB(r+1):4} = 8 -> vmcnt(4) retires exactly asyncB(r).
// As rows padded 32->40 shorts (80 B): staging ds_write was a 32-way bank
// conflict (64 lanes x 64-B stride); pad cuts write to 8-way.
__global__ __launch_bounds__(256, 2) void o_gemm(
    const float* __restrict__ att12, const float* __restrict__ att3,
    const unsigned short* __restrict__ vT, unsigned short* __restrict__ U) {
  const int bh = blockIdx.x;
  const int b = bh >> 3, h = bh & 7;
  const int t = threadIdx.x, lane = t & 63, wave = t >> 6;

  __shared__ __align__(16) unsigned short As[2][4 * 64 * 40];  // 40 KB padded
  __shared__ __align__(16) unsigned short Bs[3][4 * 64 * 32];  // 48 KB triple
  __shared__ float Ored[64 * 68];
  __shared__ float Zl[4][64];
  __shared__ float rZa[64];

  const unsigned short* vTb = vT + (long)b * 2097152 + (long)h * 64 * 4096;
  const int gq = t & 63, gw = t >> 6;          // A-gen: (k-window = wave, q)
  const float* a3row = att3 + ((long)bh * 64 + gq) * 256;
  const float* a12b = att12 + (long)b * 32768 + h * 16;
  const int l16 = lane & 15, quad = lane >> 4;

  f32x4 acc[4][4];
#pragma unroll
  for (int i = 0; i < 4; ++i)
#pragma unroll
    for (int j = 0; j < 4; ++j) acc[i][j] = (f32x4){0.f, 0.f, 0.f, 0.f};
  float zacc = 0.f;

  unsigned int pk[16];
  auto genexp = [&](int r) {
    int kbase = gw * 1024 + r * 32;
    int ch = kbase >> 8, fh = (kbase >> 6) & 3, cw0 = (kbase >> 2) & 15;
    f32x4 y0 = *(const f32x4*)(a3row + ch * 16 + cw0);
    f32x4 y1 = *(const f32x4*)(a3row + ch * 16 + cw0 + 4);
    const float* ap = a12b + ch * 2048 + cw0 * 128 + fh * 4;
#pragma unroll
    for (int cw = 0; cw < 8; ++cw) {
      float y = (cw < 4) ? y0[cw] : y1[cw - 4];
      f32x4 x = *(const f32x4*)(ap + cw * 128);
      float e0 = __expf(x[0] * y), e1 = __expf(x[1] * y);
      float e2 = __expf(x[2] * y), e3 = __expf(x[3] * y);
      zacc += (e0 + e1) + (e2 + e3);
      pk[cw * 2] = pk2(e0, e1);
      pk[cw * 2 + 1] = pk2(e2, e3);
    }
  };
  auto asyncB = [&](int rr, int slot) {
    const int rc = (rr < 32) ? rr : 0;   // clamp: uniform dummy at tail
#pragma unroll
    for (int s = 0; s < 4; ++s) {
      int row = t >> 2, kq = (t & 3) * 8;
      int kk = s * 1024 + rc * 32 + kq;
      gld_lds16(vTb + (long)row * 4096 + kk, (char*)&Bs[slot][0] + s * 4096 + wave * 1024);
    }
  };

  asyncB(0, 0);
  asyncB(1, 1);
  genexp(0);

  int slotR = 0, slotW = 2;
  for (int r = 0; r < 32; ++r) {
    const int abuf = r & 1;
    // write exps(r) regs -> As[abuf] (padded rows: 8-way instead of 32-way)
    {
      unsigned short* dst = &As[abuf][gw * 2560 + gq * 40];
#pragma unroll
      for (int g = 0; g < 4; ++g)
        *(u32x4*)(dst + g * 8) = (u32x4){pk[g * 4], pk[g * 4 + 1], pk[g * 4 + 2], pk[g * 4 + 3]};
    }
    // own ds_writes done + asyncB(r) landed; asyncB(r+1) stays in flight
    asm volatile("s_waitcnt vmcnt(4) lgkmcnt(0)" ::: "memory");
    __builtin_amdgcn_s_barrier();
    asm volatile("" ::: "memory");
    asyncB(r + 2, slotW);   // slot last read at iter r-1: safe after barrier(r)
    asm volatile("" ::: "memory");
    bf16x8 af[4], bfv[4];
#pragma unroll
    for (int i = 0; i < 4; ++i)
      af[i] = *(const bf16x8*)(&As[abuf][wave * 2560 + (i * 16 + l16) * 40 + quad * 8]);
#pragma unroll
    for (int j = 0; j < 4; ++j)
      bfv[j] = *(const bf16x8*)(&Bs[slotR][wave * 2048 + (j * 16 + l16) * 32 + quad * 8]);
#pragma unroll
    for (int i = 0; i < 4; ++i)
#pragma unroll
      for (int j = 0; j < 4; ++j)
        acc[i][j] = __builtin_amdgcn_mfma_f32_16x16x32_bf16(af[i], bfv[j], acc[i][j], 0, 0, 0);
    if (r < 31) genexp(r + 1);   // VALU overlaps MFMA execution
    slotR = (slotR == 2) ? 0 : slotR + 1;
    slotW = (slotW == 2) ? 0 : slotW + 1;
  }
  asm volatile("s_waitcnt vmcnt(0)" ::: "memory");   // drain tail dummies

  Zl[gw][gq] = zacc;
  __syncthreads();
  if (t < 64) rZa[t] = 1.0f / (Zl[0][t] + Zl[1][t] + Zl[2][t] + Zl[3][t]);
  // sum the 4 wave-accumulators (disjoint k-slices) into Ored
#pragma unroll
  for (int w = 0; w < 4; ++w) {
    if (wave == w) {
#pragma unroll
      for (int i = 0; i < 4; ++i)
#pragma unroll
        for (int j = 0; j < 4; ++j) {
          int col = j * 16 + l16;
#pragma unroll
          for (int rr = 0; rr < 4; ++rr) {
            int row = i * 16 + quad * 4 + rr;
            if (w == 0) Ored[row * 68 + col] = acc[i][j][rr];
            else Ored[row * 68 + col] += acc[i][j][rr];
          }
        }
    }
    __syncthreads();
  }
  // normalize + store bf16: U[(b*64+q)*512 + h*64 + dv]
  {
    int q = t >> 2, dv0 = (t & 3) * 16;
    float rz = rZa[q];
    unsigned short* up = U + ((long)(b * 64 + q)) * 512 + h * 64 + dv0;
    u32x4 o0, o1;
#pragma unroll
    for (int j = 0; j < 4; ++j)
      o0[j] = pk2(Ored[q * 68 + dv0 + 2 * j] * rz, Ored[q * 68 + dv0 + 2 * j + 1] * rz);
#pragma unroll
    for (int j = 0; j < 4; ++j)
      o1[j] = pk2(Ored[q * 68 + dv0 + 8 + 2 * j] * rz, Ored[q * 68 + dv0 + 9 + 2 * j] * rz);
    *(u32x4*)(up) = o0;
    *(u32x4*)(up + 8) = o1;
  }
}

// ---------------------------------------------------------------------------
// Final projection: out[(b,q)][e] = U (2048x512) x Wo^T + bias2
// Same T4 protocol: triple-buffered stage 2 deep, one raw barrier per K-step.
// Steady FIFO at pre-barrier wait: {S(r):2, S(r+1):2} = 4 -> vmcnt(2).
template <int BM, int BN>
__global__ __launch_bounds__(256, 2) void gemm_bt(
    const unsigned short* __restrict__ A, const unsigned short* __restrict__ Bt,
    float* __restrict__ C, const float* __restrict__ bias,
    int K, int lda, int ldb, int ldc) {
  constexpr int BK = 32;
  const int t = threadIdx.x;
  const int lane = t & 63;
  const int wave = t >> 6;
  const int m0 = blockIdx.y * BM;
  const int n0 = blockIdx.x * BN;

  A += (long)m0 * lda;
  Bt += (long)n0 * ldb;

  __shared__ __align__(16) unsigned short As[3][BM * BK];
  __shared__ __align__(16) unsigned short Bs[3][BN * BK];

  constexpr int TM = BM / 32;
  constexpr int TN = BN / 32;
  const int wm = (wave >> 1) * (BM / 2);
  const int wn = (wave & 1) * (BN / 2);
  const int l16 = lane & 15;
  const int quad = lane >> 4;

  f32x4 acc[TM][TN];
#pragma unroll
  for (int i = 0; i < TM; ++i)
#pragma unroll
    for (int j = 0; j < TN; ++j) acc[i][j] = (f32x4){0.f, 0.f, 0.f, 0.f};

  constexpr int ASHOT = (BM * 4) / 256;
  constexpr int BSHOT = (BN * 4) / 256;
  const int NIT = K / BK;

  auto stage = [&](int rr, int slot) {
    const int k0 = ((rr < NIT) ? rr : 0) * BK;   // clamp: uniform dummy tail
#pragma unroll
    for (int s = 0; s < ASHOT; ++s) {
      int li = s * 256 + t;
      int row = li >> 2, kq = (li & 3) * 8;
      gld_lds16(A + (long)row * lda + k0 + kq,
                (char*)&As[slot][0] + (s * 256 + wave * 64) * 16);
    }
#pragma unroll
    for (int s = 0; s < BSHOT; ++s) {
      int li = s * 256 + t;
      int row = li >> 2, kq = (li & 3) * 8;
      gld_lds16(Bt + (long)row * ldb + k0 + kq,
                (char*)&Bs[slot][0] + (s * 256 + wave * 64) * 16);
    }
  };

  stage(0, 0);
  stage(1, 1);

  int slotR = 0, slotW = 2;
  for (int r = 0; r < NIT; ++r) {
    asm volatile("s_waitcnt vmcnt(2)" ::: "memory");   // stage(r) landed
    __builtin_amdgcn_s_barrier();
    asm volatile("" ::: "memory");
    stage(r + 2, slotW);
    asm volatile("" ::: "memory");
    bf16x8 af[TM], bfv[TN];
#pragma unroll
    for (int i = 0; i < TM; ++i)
      af[i] = *(const bf16x8*)(&As[slotR][(wm + i * 16 + l16) * BK + quad * 8]);
#pragma unroll
    for (int j = 0; j < TN; ++j)
      bfv[j] = *(const bf16x8*)(&Bs[slotR][(wn + j * 16 + l16) * BK + quad * 8]);
#pragma unroll
    for (int i = 0; i < TM; ++i)
#pragma unroll
      for (int j = 0; j < TN; ++j)
        acc[i][j] = __builtin_amdgcn_mfma_f32_16x16x32_bf16(af[i], bfv[j], acc[i][j], 0, 0, 0);
    slotR = (slotR == 2) ? 0 : slotR + 1;
    slotW = (slotW == 2) ? 0 : slotW + 1;
  }
  asm volatile("s_waitcnt vmcnt(0)" ::: "memory");   // drain tail dummies

#pragma unroll
  for (int i = 0; i < TM; ++i) {
#pragma unroll
    for (int j = 0; j < TN; ++j) {
      int col = wn + j * 16 + l16;
#pragma unroll
      for (int r = 0; r < 4; ++r) {
        int row = wm + i * 16 + quad * 4 + r;
        C[(long)(m0 + row) * ldc + (n0 + col)] = acc[i][j][r] + bias[n0 + col];
      }
    }
  }
}

// ---------------------------------------------------------------------------
extern "C" void kernel_launch(void* const* d_in, const int* in_sizes, int n_in,
                              void* d_out, int out_size, void* d_ws, size_t ws_size,
                              hipStream_t stream) {
  const float* att12 = (const float*)d_in[0];
  const float* att3  = (const float*)d_in[1];
  const float* values = (const float*)d_in[2];
  const float* W_v = (const float*)d_in[3];
  const float* b_v = (const float*)d_in[4];
  const float* W_o = (const float*)d_in[5];
  const float* b_o = (const float*)d_in[6];
  float* out = (float*)d_out;

  char* ws = (char*)d_ws;
  unsigned short* vT    = (unsigned short*)(ws);               // 128 MB [32][512][4096]
  unsigned short* U     = (unsigned short*)(ws + 134217728L);  // 2 MB [2048][512]
  unsigned short* Wvb   = (unsigned short*)(ws + 136314880L);  // 512 KB
  unsigned short* Wob   = (unsigned short*)(ws + 136839168L);  // 512 KB
  float*          bias2 = (float*)(ws + 137363456L);           // 2 KB

  prep<<<dim3(514), dim3(256), 0, stream>>>(W_v, W_o, b_v, b_o, Wvb, Wob, bias2);

  vt_gemm<<<dim3(32, 2, 32), dim3(256), 0, stream>>>(Wvb, values, vT);

  o_gemm<<<dim3(256), dim3(256), 0, stream>>>(att12, att3, vT, U);

  gemm_bt<64, 64><<<dim3(8, 32), dim3(256), 0, stream>>>(
      U, Wob, out, bias2, 512, 512, 512, 512);

  (void)in_sizes; (void)n_in; (void)out_size; (void)ws_size;
}